// Round 4
// baseline (285.700 us; speedup 1.0000x reference)
//
#include <hip/hip_runtime.h>
#include <hip/hip_bf16.h>
#include <math.h>

// B=4, C=256, N=4096, QP=32.
// ws: qH[b][n][32] f16, kH[b][n][32] f16, vHT[b][c][n] f16, ms[b][n] f32.
// K1 qkv: MFMA GEMM rows=concat[Wv;Wq;Wk]=320.
// K2 mpass: ms[b][j] = max_i (q_i . k_j)  (f16 MFMA, f32 max).
// K3 attn: out^T[j,c] = sum_i exp(s-m) v  -- S D-layout converted in-register
//          to PV A-layout (shfl_xor 32), NO LDS P, NO barriers in K-loop.

#define NBATCH 4
#define CDIM   256
#define NSEQ   4096
#define QPDIM  32

typedef _Float16 half8_t  __attribute__((ext_vector_type(8)));
typedef _Float16 half2_t  __attribute__((ext_vector_type(2)));
typedef float    floatx4  __attribute__((ext_vector_type(4)));
typedef float    floatx16 __attribute__((ext_vector_type(16)));

union H8 { half8_t h8; half2_t h2[4]; int i32[4]; };

// ---------------------------------------------------------------------------
// K1: qkv GEMM. grid = 4b x 128 nt(32 n) x 2 mh(160 rows) = 1024 blocks,
// 128 thr (2 waves). Wave w: rows [mh*160 + w*80, +80) = 5 m-tiles of 16.
// x-tile [256c x 32n] staged transposed to LDS f16 (conflict-free writes).
// ---------------------------------------------------------------------------
__global__ __launch_bounds__(128, 2) void qkv_kernel(
    const float* __restrict__ x,
    const float* __restrict__ Wq, const float* __restrict__ bq,
    const float* __restrict__ Wk, const float* __restrict__ bk,
    const float* __restrict__ Wv, const float* __restrict__ bv,
    _Float16* __restrict__ qH, _Float16* __restrict__ kH,
    _Float16* __restrict__ vHT)
{
    __shared__ _Float16 xT[32][264];   // [n][c]

    const int blk  = blockIdx.x;
    const int slot = blk & 7;
    const int b    = slot >> 1;
    const int idx  = ((blk >> 3) << 1) | (slot & 1);  // 0..255
    const int mh   = idx >> 7;                        // 0..1
    const int n0   = (idx & 127) << 5;                // n tile base
    const int t    = threadIdx.x;                     // 0..127
    const int w    = t >> 6;
    const int lane = t & 63;
    const int quad = lane >> 4;
    const int col  = lane & 15;

    // ---- stage x[b, :, n0..n0+31] transposed into xT (f16) ----
    #pragma unroll
    for (int rep = 0; rep < 2; ++rep) {
        const int c = t + rep * 128;
        const float* xrow = x + ((size_t)(b * CDIM + c)) * NSEQ + n0;
        #pragma unroll
        for (int g = 0; g < 8; ++g) {
            float4 f = ((const float4*)xrow)[g];
            xT[g * 4 + 0][c] = (_Float16)f.x;
            xT[g * 4 + 1][c] = (_Float16)f.y;
            xT[g * 4 + 2][c] = (_Float16)f.z;
            xT[g * 4 + 3][c] = (_Float16)f.w;
        }
    }

    // ---- per-tile W pointers (wave-uniform bases) ----
    const int rbase = mh * 160 + w * 80;
    const float* wptr[5]; const float* bptr[5]; int rl5[5]; int glob5[5];
    #pragma unroll
    for (int t5 = 0; t5 < 5; ++t5) {
        const int base = rbase + t5 * 16;
        const float* Wp; const float* bp; int rl;
        if (base < 256)      { Wp = Wv; bp = bv; rl = base; }
        else if (base < 288) { Wp = Wq; bp = bq; rl = base - 256; }
        else                 { Wp = Wk; bp = bk; rl = base - 288; }
        wptr[t5] = Wp + (size_t)(rl + col) * CDIM + quad * 8;
        bptr[t5] = bp + rl;
        rl5[t5] = rl; glob5[t5] = base;
    }
    __syncthreads();

    // ---- GEMM ----
    floatx4 acc[5][2];
    #pragma unroll
    for (int t5 = 0; t5 < 5; ++t5) {
        acc[t5][0] = (floatx4){0.f, 0.f, 0.f, 0.f};
        acc[t5][1] = (floatx4){0.f, 0.f, 0.f, 0.f};
    }
    #pragma unroll
    for (int ks = 0; ks < 8; ++ks) {
        half8_t bf0 = *(const half8_t*)&xT[col][ks * 32 + quad * 8];
        half8_t bf1 = *(const half8_t*)&xT[16 + col][ks * 32 + quad * 8];
        #pragma unroll
        for (int t5 = 0; t5 < 5; ++t5) {
            float4 f0 = *(const float4*)(wptr[t5] + ks * 32);
            float4 f1 = *(const float4*)(wptr[t5] + ks * 32 + 4);
            H8 a;
            a.h2[0] = (half2_t){(_Float16)f0.x, (_Float16)f0.y};
            a.h2[1] = (half2_t){(_Float16)f0.z, (_Float16)f0.w};
            a.h2[2] = (half2_t){(_Float16)f1.x, (_Float16)f1.y};
            a.h2[3] = (half2_t){(_Float16)f1.z, (_Float16)f1.w};
            acc[t5][0] = __builtin_amdgcn_mfma_f32_16x16x32_f16(a.h8, bf0, acc[t5][0], 0, 0, 0);
            acc[t5][1] = __builtin_amdgcn_mfma_f32_16x16x32_f16(a.h8, bf1, acc[t5][1], 0, 0, 0);
        }
    }

    // ---- epilogue: bias + store ----
    #pragma unroll
    for (int t5 = 0; t5 < 5; ++t5) {
        const int gbase = glob5[t5];
        #pragma unroll
        for (int reg = 0; reg < 4; ++reg) {
            const int grow = gbase + quad * 4 + reg;
            const float bias = bptr[t5][quad * 4 + reg];
            #pragma unroll
            for (int nt = 0; nt < 2; ++nt) {
                const int n = n0 + nt * 16 + col;
                const float val = acc[t5][nt][reg] + bias;
                if (grow < 256)
                    vHT[((size_t)(b * CDIM + grow)) * NSEQ + n] = (_Float16)val;
                else if (grow < 288)
                    qH[((size_t)(b * NSEQ + n)) * QPDIM + (grow - 256)] = (_Float16)val;
                else
                    kH[((size_t)(b * NSEQ + n)) * QPDIM + (grow - 288)] = (_Float16)val;
            }
        }
    }
}

// ---------------------------------------------------------------------------
// K2: mpass. grid = 4b x 64 jblk(64 j) = 256 blocks, 256 thr.
// wave w: ih = w&1 (i half), jt = w>>1 (32-j tile). ms[b][j] = col max.
// ---------------------------------------------------------------------------
__global__ __launch_bounds__(256, 2) void mpass_kernel(
    const _Float16* __restrict__ qH, const _Float16* __restrict__ kH,
    float* __restrict__ ms)
{
    __shared__ float wmax[4][32];

    const int blk  = blockIdx.x;
    const int slot = blk & 7;
    const int b    = slot >> 1;
    const int jblk = ((blk >> 3) << 1) | (slot & 1);  // 0..63
    const int t    = threadIdx.x;
    const int w    = t >> 6;
    const int lane = t & 63;
    const int l5   = lane >> 5;
    const int ih   = w & 1, jt = w >> 1;

    const _Float16* qg = qH + (size_t)b * NSEQ * QPDIM;
    const int j = jblk * 64 + jt * 32 + (lane & 31);
    const half8_t kb0 = *(const half8_t*)(
        kH + ((size_t)(b * NSEQ + j)) * QPDIM + l5 * 8);
    const half8_t kb1 = *(const half8_t*)(
        kH + ((size_t)(b * NSEQ + j)) * QPDIM + 16 + l5 * 8);

    float mx = -1e30f;
    const _Float16* qbase = qg + (size_t)(ih * 2048 + (lane & 31)) * QPDIM + l5 * 8;
    for (int cc = 0; cc < 64; ++cc) {
        const _Float16* qp = qbase + (size_t)cc * 32 * QPDIM;
        half8_t qa0 = *(const half8_t*)qp;
        half8_t qa1 = *(const half8_t*)(qp + 16);
        floatx16 S = __builtin_amdgcn_mfma_f32_32x32x16_f16(
            qa0, kb0, (floatx16){0.f}, 0, 0, 0);
        S = __builtin_amdgcn_mfma_f32_32x32x16_f16(qa1, kb1, S, 0, 0, 0);
        #pragma unroll
        for (int r = 0; r < 16; ++r) mx = fmaxf(mx, S[r]);
    }
    mx = fmaxf(mx, __shfl_xor(mx, 32));
    if (lane < 32) wmax[w][lane] = mx;
    __syncthreads();
    if (t < 64) {
        const int jt2 = t >> 5, c = t & 31;
        ms[(size_t)b * NSEQ + jblk * 64 + jt2 * 32 + c] =
            fmaxf(wmax[jt2 * 2][c], wmax[jt2 * 2 + 1][c]);
    }
}

// ---------------------------------------------------------------------------
// K3: attn. grid = 512 blocks (4b x 32 jblk(128 j) x 4 ch(64 c)), 256 thr.
// Wave w: j0w = jblk*128 + w*32 (32 j), c range = ch*64 (2 c-tiles of 32).
// Per 32-i chunk: S (2 MFMA) -> exp -> in-register D->A transform (8 shfl)
// -> PV (4 MFMA, v B-frags from global). No barriers, no LDS P.
// ---------------------------------------------------------------------------
__global__ __launch_bounds__(256, 2) void attn_kernel(
    const _Float16* __restrict__ qH, const _Float16* __restrict__ kH,
    const _Float16* __restrict__ vHT, const float* __restrict__ ms,
    const float* __restrict__ x, const float* __restrict__ gamma,
    float* __restrict__ out)
{
    __shared__ float rvs[4][32];

    const int blk  = blockIdx.x;
    const int slot = blk & 7;
    const int b    = slot >> 1;
    const int idx  = ((blk >> 3) << 1) | (slot & 1);  // 0..127
    const int ch   = idx >> 5;                        // 0..3
    const int jblk = idx & 31;                        // 0..31
    const int t    = threadIdx.x;
    const int w    = t >> 6;
    const int lane = t & 63;
    const int l5   = lane >> 5;
    const int lj   = lane & 31;
    const int j0w  = jblk * 128 + w * 32;
    const int c0   = ch * 64;

    const _Float16* qg = qH + (size_t)b * NSEQ * QPDIM;
    const _Float16* vg = vHT + (size_t)b * CDIM * NSEQ;

    // persistent k B-frags (n = j)
    const half8_t kb0 = *(const half8_t*)(
        kH + ((size_t)(b * NSEQ + j0w + lj)) * QPDIM + l5 * 8);
    const half8_t kb1 = *(const half8_t*)(
        kH + ((size_t)(b * NSEQ + j0w + lj)) * QPDIM + 16 + l5 * 8);
    const float mfix = ms[(size_t)b * NSEQ + j0w + lj];

    floatx16 acc0 = (floatx16){0.f};
    floatx16 acc1 = (floatx16){0.f};
    float lp = 0.0f;

    const _Float16* qb = qg + (size_t)lj * QPDIM + l5 * 8;
    const _Float16* vb0 = vg + (size_t)(c0 + lj) * NSEQ + l5 * 8;
    const _Float16* vb1 = vg + (size_t)(c0 + 32 + lj) * NSEQ + l5 * 8;

    // prefetch chunk 0
    half8_t qa0 = *(const half8_t*)(qb);
    half8_t qa1 = *(const half8_t*)(qb + 16);
    half8_t v00 = *(const half8_t*)(vb0);
    half8_t v01 = *(const half8_t*)(vb0 + 16);
    half8_t v10 = *(const half8_t*)(vb1);
    half8_t v11 = *(const half8_t*)(vb1 + 16);

    for (int i0 = 0; i0 < NSEQ; i0 += 32) {
        const int inext = (i0 + 32 < NSEQ) ? i0 + 32 : 0;
        // prefetch next chunk
        half8_t nqa0 = *(const half8_t*)(qb + (size_t)inext * QPDIM);
        half8_t nqa1 = *(const half8_t*)(qb + (size_t)inext * QPDIM + 16);
        half8_t nv00 = *(const half8_t*)(vb0 + inext);
        half8_t nv01 = *(const half8_t*)(vb0 + inext + 16);
        half8_t nv10 = *(const half8_t*)(vb1 + inext);
        half8_t nv11 = *(const half8_t*)(vb1 + inext + 16);

        // S = q . k^T : D[m=i][n=j], lane: j = lj, regs = i
        floatx16 S = __builtin_amdgcn_mfma_f32_32x32x16_f16(
            qa0, kb0, (floatx16){0.f}, 0, 0, 0);
        S = __builtin_amdgcn_mfma_f32_32x32x16_f16(qa1, kb1, S, 0, 0, 0);

        // exp + pack (pk[r] covers i pairs; D row = (reg&3)+8*(reg>>2)+4*l5)
        H8 lo, hi;   // lo: pk0..3 (i 0..3,8..11 +4*l5), hi: pk4..7
        float ls = 0.0f;
        #pragma unroll
        for (int r = 0; r < 8; r += 2) {
            float pa = __expf(S[r]     - mfix);
            float pb = __expf(S[r + 1] - mfix);
            ls += pa + pb;
            lo.h2[r >> 1] = (half2_t){(_Float16)pa, (_Float16)pb};
        }
        #pragma unroll
        for (int r = 8; r < 16; r += 2) {
            float pa = __expf(S[r]     - mfix);
            float pb = __expf(S[r + 1] - mfix);
            ls += pa + pb;
            hi.h2[(r - 8) >> 1] = (half2_t){(_Float16)pa, (_Float16)pb};
        }
        lp += ls;

        // D -> A transform: shfl_xor 32 + select
        H8 shl, shh;
        #pragma unroll
        for (int r = 0; r < 4; ++r) {
            shl.i32[r] = __shfl_xor(lo.i32[r], 32);
            shh.i32[r] = __shfl_xor(hi.i32[r], 32);
        }
        const bool high = (l5 != 0);
        H8 A0, A1;
        // A0 (k-step 0, i 0..15): low: [pk0,pk1,sh0,sh1]; high: [sh2,sh3,pk2,pk3]
        A0.i32[0] = high ? shl.i32[2] : lo.i32[0];
        A0.i32[1] = high ? shl.i32[3] : lo.i32[1];
        A0.i32[2] = high ? lo.i32[2]  : shl.i32[0];
        A0.i32[3] = high ? lo.i32[3]  : shl.i32[1];
        // A1 (k-step 1, i 16..31): low: [pk4,pk5,sh4,sh5]; high: [sh6,sh7,pk6,pk7]
        A1.i32[0] = high ? shh.i32[2] : hi.i32[0];
        A1.i32[1] = high ? shh.i32[3] : hi.i32[1];
        A1.i32[2] = high ? hi.i32[2]  : shh.i32[0];
        A1.i32[3] = high ? hi.i32[3]  : shh.i32[1];

        // PV: out^T[m=j][n=c] += P^T . v
        acc0 = __builtin_amdgcn_mfma_f32_32x32x16_f16(A0.h8, v00, acc0, 0, 0, 0);
        acc0 = __builtin_amdgcn_mfma_f32_32x32x16_f16(A1.h8, v01, acc0, 0, 0, 0);
        acc1 = __builtin_amdgcn_mfma_f32_32x32x16_f16(A0.h8, v10, acc1, 0, 0, 0);
        acc1 = __builtin_amdgcn_mfma_f32_32x32x16_f16(A1.h8, v11, acc1, 0, 0, 0);

        qa0 = nqa0; qa1 = nqa1;
        v00 = nv00; v01 = nv01; v10 = nv10; v11 = nv11;
    }

    // ---- l, rv ----
    lp += __shfl_xor(lp, 32);            // full column sum for j = j0w+lj
    if (lane < 32) rvs[w][lane] = gamma[0] / lp;
    __syncthreads();

    // ---- epilogue: out[c][j] = acc*rv + x ----
    #pragma unroll
    for (int reg = 0; reg < 16; ++reg) {
        const int jl = (reg & 3) + 8 * (reg >> 2) + 4 * l5;
        const float rv = rvs[w][jl];
        const size_t jg = (size_t)(j0w + jl);
        {
            const int c = c0 + lj;
            const size_t off = ((size_t)(b * CDIM + c)) * NSEQ + jg;
            out[off] = acc0[reg] * rv + x[off];
        }
        {
            const int c = c0 + 32 + lj;
            const size_t off = ((size_t)(b * CDIM + c)) * NSEQ + jg;
            out[off] = acc1[reg] * rv + x[off];
        }
    }
}

extern "C" void kernel_launch(void* const* d_in, const int* in_sizes, int n_in,
                              void* d_out, int out_size, void* d_ws, size_t ws_size,
                              hipStream_t stream) {
    const float* x     = (const float*)d_in[0];
    const float* Wq    = (const float*)d_in[1];
    const float* bq    = (const float*)d_in[2];
    const float* Wk    = (const float*)d_in[3];
    const float* bk    = (const float*)d_in[4];
    const float* Wv    = (const float*)d_in[5];
    const float* bv    = (const float*)d_in[6];
    const float* gamma = (const float*)d_in[7];
    float* out = (float*)d_out;

    _Float16* w16 = (_Float16*)d_ws;
    _Float16* qH  = w16;                                       // 1 MB
    _Float16* kH  = w16 + (size_t)NBATCH * NSEQ * QPDIM;       // 1 MB
    _Float16* vHT = w16 + (size_t)2 * NBATCH * NSEQ * QPDIM;   // 8 MB
    float*    ms  = (float*)(w16 + (size_t)2 * NBATCH * NSEQ * QPDIM
                                 + (size_t)NBATCH * CDIM * NSEQ);  // 64 KB

    qkv_kernel<<<1024, 128, 0, stream>>>(x, Wq, bq, Wk, bk, Wv, bv, qH, kH, vHT);
    mpass_kernel<<<256, 256, 0, stream>>>(qH, kH, ms);
    attn_kernel<<<512, 256, 0, stream>>>(qH, kH, vHT, ms, x, gamma, out);
}

// Round 5
// 212.785 us; speedup vs baseline: 1.3427x; 1.3427x over previous
//
#include <hip/hip_runtime.h>
#include <hip/hip_bf16.h>
#include <math.h>

// B=4, C=256, N=4096, QP=32.
// ws: qH[b][n][32] f16, kH[b][n][32] f16, vHT[b][c][n] f16,
//     wH[320][256] f16 (concat Wv;Wq;Wk), ms4[4][b][n] f32 (partial col max).
// K0 wprep: W fp32 -> f16 once.
// K1 qkv: MFMA GEMM, 2560 blocks x 2 waves.
// K2 mpass: partial max over i quarters (1024 blocks).
// K3 attn: per block 64j x 64c; per 64-i tile: phase1 S+exp -> PT LDS
//          (write IS the D->A transform), phase2 PV from DMA'd v tile.
//          2 barriers/tile, v double-buffered via global_load_lds.

#define NBATCH 4
#define CDIM   256
#define NSEQ   4096
#define QPDIM  32

typedef _Float16 half8_t  __attribute__((ext_vector_type(8)));
typedef _Float16 half2_t  __attribute__((ext_vector_type(2)));
typedef float    floatx4  __attribute__((ext_vector_type(4)));
typedef float    floatx16 __attribute__((ext_vector_type(16)));

// ---------------------------------------------------------------------------
// K0: W -> f16. 40 blocks x 256 thr x 8 elems.
// ---------------------------------------------------------------------------
__global__ __launch_bounds__(256) void wprep_kernel(
    const float* __restrict__ Wv, const float* __restrict__ Wq,
    const float* __restrict__ Wk, _Float16* __restrict__ wH)
{
    const int idx = blockIdx.x * 256 + threadIdx.x;   // 0..10239
    const int e = idx * 8;
    const int r = e >> 8, c = e & 255;
    const float* src;
    if (r < 256)      src = Wv + (size_t)r * 256 + c;
    else if (r < 288) src = Wq + (size_t)(r - 256) * 256 + c;
    else              src = Wk + (size_t)(r - 288) * 256 + c;
    float4 f0 = ((const float4*)src)[0];
    float4 f1 = ((const float4*)src)[1];
    half8_t h;
    h[0] = (_Float16)f0.x; h[1] = (_Float16)f0.y;
    h[2] = (_Float16)f0.z; h[3] = (_Float16)f0.w;
    h[4] = (_Float16)f1.x; h[5] = (_Float16)f1.y;
    h[6] = (_Float16)f1.z; h[7] = (_Float16)f1.w;
    *(half8_t*)(wH + (size_t)r * 256 + c) = h;
}

// ---------------------------------------------------------------------------
// K1: qkv GEMM. grid = 5 mg x 4 b x 128 nt = 2560 blocks, 128 thr (2 waves).
// Wave w: rows mg*64 + w*32 (2 m-tiles of 16) x 32 n x k=256.
// A from wH f16 (L2-hot), B from transposed x LDS tile.
// ---------------------------------------------------------------------------
__global__ __launch_bounds__(128, 4) void qkv_kernel(
    const float* __restrict__ x, const _Float16* __restrict__ wH,
    const float* __restrict__ bq, const float* __restrict__ bk,
    const float* __restrict__ bv,
    _Float16* __restrict__ qH, _Float16* __restrict__ kH,
    _Float16* __restrict__ vHT)
{
    __shared__ _Float16 xT[32][264];   // [n][c]

    const int blk  = blockIdx.x;
    const int slot = blk & 7;
    const int b    = slot >> 1;
    const int idx  = ((blk >> 3) << 1) | (slot & 1);  // 0..639
    const int mg   = idx % 5;
    const int n0   = (idx / 5) << 5;
    const int t    = threadIdx.x;
    const int w    = t >> 6;
    const int lane = t & 63;
    const int quad = lane >> 4;
    const int col  = lane & 15;

    // stage x[b,:,n0..n0+31] transposed -> f16
    #pragma unroll
    for (int rep = 0; rep < 2; ++rep) {
        const int c = t + rep * 128;
        const float* xrow = x + ((size_t)(b * CDIM + c)) * NSEQ + n0;
        #pragma unroll
        for (int g = 0; g < 8; ++g) {
            float4 f = ((const float4*)xrow)[g];
            xT[g * 4 + 0][c] = (_Float16)f.x;
            xT[g * 4 + 1][c] = (_Float16)f.y;
            xT[g * 4 + 2][c] = (_Float16)f.z;
            xT[g * 4 + 3][c] = (_Float16)f.w;
        }
    }
    __syncthreads();

    const int rb = mg * 64 + w * 32;      // wave's first row (2 tiles of 16)
    floatx4 acc[2][2];
    #pragma unroll
    for (int mt = 0; mt < 2; ++mt) {
        acc[mt][0] = (floatx4){0.f, 0.f, 0.f, 0.f};
        acc[mt][1] = (floatx4){0.f, 0.f, 0.f, 0.f};
    }
    #pragma unroll
    for (int ks = 0; ks < 8; ++ks) {
        half8_t bf0 = *(const half8_t*)&xT[col][ks * 32 + quad * 8];
        half8_t bf1 = *(const half8_t*)&xT[16 + col][ks * 32 + quad * 8];
        #pragma unroll
        for (int mt = 0; mt < 2; ++mt) {
            half8_t a = *(const half8_t*)(
                wH + (size_t)(rb + mt * 16 + col) * 256 + ks * 32 + quad * 8);
            acc[mt][0] = __builtin_amdgcn_mfma_f32_16x16x32_f16(a, bf0, acc[mt][0], 0, 0, 0);
            acc[mt][1] = __builtin_amdgcn_mfma_f32_16x16x32_f16(a, bf1, acc[mt][1], 0, 0, 0);
        }
    }

    // epilogue: bias + store per row type
    #pragma unroll
    for (int mt = 0; mt < 2; ++mt) {
        const int gbase = rb + mt * 16;
        const float* bp; int rl;
        if (gbase < 256)      { bp = bv; rl = gbase; }
        else if (gbase < 288) { bp = bq; rl = gbase - 256; }
        else                  { bp = bk; rl = gbase - 288; }
        #pragma unroll
        for (int reg = 0; reg < 4; ++reg) {
            const float bias = bp[rl + quad * 4 + reg];
            #pragma unroll
            for (int nt = 0; nt < 2; ++nt) {
                const int n = n0 + nt * 16 + col;
                const float val = acc[mt][nt][reg] + bias;
                if (gbase < 256)
                    vHT[((size_t)(b * CDIM + rl + quad * 4 + reg)) * NSEQ + n] = (_Float16)val;
                else if (gbase < 288)
                    qH[((size_t)(b * NSEQ + n)) * QPDIM + rl + quad * 4 + reg] = (_Float16)val;
                else
                    kH[((size_t)(b * NSEQ + n)) * QPDIM + rl + quad * 4 + reg] = (_Float16)val;
            }
        }
    }
}

// ---------------------------------------------------------------------------
// K2: mpass partial col-max. grid = 4 iq x 4 b x 64 jblk = 1024 blocks.
// Wave w: jt = w&1 (32 j), ih = w>>1 (512-i half of the 1024-i quarter).
// ---------------------------------------------------------------------------
__global__ __launch_bounds__(256, 4) void mpass_kernel(
    const _Float16* __restrict__ qH, const _Float16* __restrict__ kH,
    float* __restrict__ ms4)
{
    __shared__ float wmax[4][32];

    const int blk  = blockIdx.x;
    const int slot = blk & 7;
    const int b    = slot >> 1;
    const int idx  = ((blk >> 3) << 1) | (slot & 1);  // 0..255
    const int jblk = idx & 63;
    const int iq   = idx >> 6;
    const int t    = threadIdx.x;
    const int w    = t >> 6;
    const int lane = t & 63;
    const int l5   = lane >> 5;
    const int lj   = lane & 31;
    const int jt   = w & 1, ih = w >> 1;

    const _Float16* qg = qH + (size_t)b * NSEQ * QPDIM;
    const int j = jblk * 64 + jt * 32 + lj;
    const half8_t kb0 = *(const half8_t*)(
        kH + ((size_t)(b * NSEQ + j)) * QPDIM + l5 * 8);
    const half8_t kb1 = *(const half8_t*)(
        kH + ((size_t)(b * NSEQ + j)) * QPDIM + 16 + l5 * 8);

    float mx = -1e30f;
    const int ibase = iq * 1024 + ih * 512;
    for (int cc = 0; cc < 16; ++cc) {
        const _Float16* qp = qg + (size_t)(ibase + cc * 32 + lj) * QPDIM + l5 * 8;
        half8_t qa0 = *(const half8_t*)qp;
        half8_t qa1 = *(const half8_t*)(qp + 16);
        floatx16 S = __builtin_amdgcn_mfma_f32_32x32x16_f16(
            qa0, kb0, (floatx16){0.f}, 0, 0, 0);
        S = __builtin_amdgcn_mfma_f32_32x32x16_f16(qa1, kb1, S, 0, 0, 0);
        #pragma unroll
        for (int r = 0; r < 16; ++r) mx = fmaxf(mx, S[r]);
    }
    mx = fmaxf(mx, __shfl_xor(mx, 32));
    if (lane < 32) wmax[w][lane] = mx;
    __syncthreads();
    if (t < 64) {
        const int jt3 = t >> 5, c = t & 31;
        ms4[(size_t)iq * (NBATCH * NSEQ) + (size_t)b * NSEQ
            + jblk * 64 + jt3 * 32 + c] = fmaxf(wmax[jt3][c], wmax[jt3 + 2][c]);
    }
}

// ---------------------------------------------------------------------------
// K3: attn. grid = 1024 blocks (4b x 64 jblk(64 j) x 4 cblk(64 c)), 256 thr.
// Phase1 wave (jh=w&1, ih=w>>1): S 32x32 tile + exp -> PT[64j][72] (transform
// baked into write addressing). Phase2 wave (jw=jh, cw=ih): 4 PV MFMAs from
// PT A-frags + XOR-swizzled v LDS tile (global_load_lds double buffer).
// ---------------------------------------------------------------------------
__global__ __launch_bounds__(256, 4) void attn_kernel(
    const _Float16* __restrict__ qH, const _Float16* __restrict__ kH,
    const _Float16* __restrict__ vHT, const float* __restrict__ ms4,
    const float* __restrict__ x, const float* __restrict__ gamma,
    float* __restrict__ out)
{
    __shared__ _Float16 vbuf[2][4096];   // [c_local 64][unit 8 ^ (c&7)][8]
    __shared__ _Float16 PT[64][72];      // [j_local][i_local], 144B rows
    __shared__ float lred[4][32];
    __shared__ float rvs[64];

    const int blk  = blockIdx.x;
    const int slot = blk & 7;
    const int b    = slot >> 1;
    const int idx  = ((blk >> 3) << 1) | (slot & 1);  // 0..255
    const int jblk = idx & 63;
    const int cblk = idx >> 6;
    const int j0   = jblk << 6;
    const int c0   = cblk << 6;
    const int t    = threadIdx.x;
    const int w    = t >> 6;
    const int lane = t & 63;
    const int l5   = lane >> 5;
    const int lj   = lane & 31;
    const int jh   = w & 1;    // phase1 j-tile, phase2 PT row-half
    const int ih   = w >> 1;   // phase1 i-half,  phase2 c-tile

    const _Float16* qg = qH + (size_t)b * NSEQ * QPDIM;
    const _Float16* vg = vHT + (size_t)b * CDIM * NSEQ;

    // persistent k B-frags for this wave's j-tile
    const half8_t kb0 = *(const half8_t*)(
        kH + ((size_t)(b * NSEQ + j0 + jh * 32 + lj)) * QPDIM + l5 * 8);
    const half8_t kb1 = *(const half8_t*)(
        kH + ((size_t)(b * NSEQ + j0 + jh * 32 + lj)) * QPDIM + 16 + l5 * 8);

    const float* msb = ms4 + (size_t)b * NSEQ + j0 + jh * 32 + lj;
    const float mfix = fmaxf(
        fmaxf(msb[0], msb[NBATCH * NSEQ]),
        fmaxf(msb[2 * NBATCH * NSEQ], msb[3 * NBATCH * NSEQ]));

    floatx16 acc = (floatx16){0.f};
    float lp = 0.0f;

    // v DMA: 2 calls/wave cover 128 units of 16B (source XOR-swizzled)
    #define DMA_V(i0_, buf_)                                                   \
        {                                                                      \
            _Pragma("unroll")                                                  \
            for (int cc = 0; cc < 2; ++cc) {                                   \
                const int u  = w * 128 + cc * 64 + lane;                       \
                const int cl = u >> 3;                                         \
                const int uu = (u & 7) ^ (cl & 7);                             \
                const _Float16* src =                                          \
                    vg + (size_t)(c0 + cl) * NSEQ + (i0_) + uu * 8;            \
                __builtin_amdgcn_global_load_lds(                              \
                    (const __attribute__((address_space(1))) void*)src,        \
                    (__attribute__((address_space(3))) void*)                  \
                        (&vbuf[buf_][u * 8]),                                  \
                    16, 0, 0);                                                 \
            }                                                                  \
        }

    DMA_V(0, 0);
    const _Float16* qb = qg + (size_t)(ih * 32 + lj) * QPDIM + l5 * 8;
    half8_t qa0 = *(const half8_t*)(qb);
    half8_t qa1 = *(const half8_t*)(qb + 16);
    __syncthreads();   // v[0] ready

    int cur = 0;
    for (int i0 = 0; i0 < NSEQ; i0 += 64) {
        // ---- phase 1: S + exp -> PT ----
        floatx16 S = __builtin_amdgcn_mfma_f32_32x32x16_f16(
            qa0, kb0, (floatx16){0.f}, 0, 0, 0);
        S = __builtin_amdgcn_mfma_f32_32x32x16_f16(qa1, kb1, S, 0, 0, 0);
        float ls = 0.0f;
        #pragma unroll
        for (int p = 0; p < 8; ++p) {
            float pa = __expf(S[2 * p]     - mfix);
            float pb = __expf(S[2 * p + 1] - mfix);
            ls += pa + pb;
            const int ip = ((2 * p) & 3) + 8 * (p >> 1) + 4 * l5;
            *(half2_t*)&PT[jh * 32 + lj][ih * 32 + ip] =
                (half2_t){(_Float16)pa, (_Float16)pb};
        }
        lp += ls;
        __syncthreads();   // B1: PT ready

        // issue next tile's v DMA + q prefetch (land by trailing barrier)
        if (i0 + 64 < NSEQ) {
            DMA_V(i0 + 64, cur ^ 1);
            qa0 = *(const half8_t*)(qb + (size_t)(i0 + 64) * QPDIM);
            qa1 = *(const half8_t*)(qb + (size_t)(i0 + 64) * QPDIM + 16);
        }

        // ---- phase 2: PV (jw = jh rows of PT, cw = ih c-tile of v) ----
        #pragma unroll
        for (int s = 0; s < 4; ++s) {
            half8_t Af = *(const half8_t*)&PT[jh * 32 + lj][s * 16 + l5 * 8];
            const int cl = ih * 32 + lj;
            const int uu = (s * 2 + l5) ^ (cl & 7);
            half8_t Bf = *(const half8_t*)&vbuf[cur][(cl * 8 + uu) * 8];
            acc = __builtin_amdgcn_mfma_f32_32x32x16_f16(Af, Bf, acc, 0, 0, 0);
        }
        cur ^= 1;
        __syncthreads();   // B_top(next): v[cur] DMA'd, PT free
    }

    // ---- l reduction + rv ----
    lp += __shfl_xor(lp, 32);
    if (lane < 32) lred[w][lj] = lp;
    __syncthreads();
    if (t < 64) {
        const int jh2 = t >> 5, c = t & 31;
        rvs[t] = gamma[0] / (lred[jh2][c] + lred[jh2 + 2][c]);
    }
    __syncthreads();

    // ---- epilogue: out[c][j] = acc*rv + x ----
    #pragma unroll
    for (int reg = 0; reg < 16; ++reg) {
        const int jl = (reg & 3) + 8 * (reg >> 2) + 4 * l5 + jh * 32;
        const float rv = rvs[jl];
        const int c_ = c0 + ih * 32 + lj;
        const size_t off = ((size_t)(b * CDIM + c_)) * NSEQ + j0 + jl;
        out[off] = acc[reg] * rv + x[off];
    }
}

extern "C" void kernel_launch(void* const* d_in, const int* in_sizes, int n_in,
                              void* d_out, int out_size, void* d_ws, size_t ws_size,
                              hipStream_t stream) {
    const float* x     = (const float*)d_in[0];
    const float* Wq    = (const float*)d_in[1];
    const float* bq    = (const float*)d_in[2];
    const float* Wk    = (const float*)d_in[3];
    const float* bk    = (const float*)d_in[4];
    const float* Wv    = (const float*)d_in[5];
    const float* bv    = (const float*)d_in[6];
    const float* gamma = (const float*)d_in[7];
    float* out = (float*)d_out;

    _Float16* w16 = (_Float16*)d_ws;
    _Float16* qH  = w16;                                        // 1 MB
    _Float16* kH  = qH + (size_t)NBATCH * NSEQ * QPDIM;         // 1 MB
    _Float16* vHT = kH + (size_t)NBATCH * NSEQ * QPDIM;         // 8 MB
    _Float16* wH  = vHT + (size_t)NBATCH * CDIM * NSEQ;         // 160 KB
    float*    ms4 = (float*)(wH + (size_t)320 * 256);           // 256 KB

    wprep_kernel<<<40, 256, 0, stream>>>(Wv, Wq, Wk, wH);
    qkv_kernel<<<2560, 128, 0, stream>>>(x, wH, bq, bk, bv, qH, kH, vHT);
    mpass_kernel<<<1024, 256, 0, stream>>>(qH, kH, ms4);
    attn_kernel<<<1024, 256, 0, stream>>>(qH, kH, vHT, ms4, x, gamma, out);
}

// Round 7
// 184.146 us; speedup vs baseline: 1.5515x; 1.1555x over previous
//
#include <hip/hip_runtime.h>
#include <hip/hip_bf16.h>
#include <math.h>

// B=4, C=256, N=4096, QP=32.
// ws: qH[b][n][32] f16 (PRE-SCALED by log2e), kH[b][n][32] f16,
//     vHT[b][c][n] f16, wH[320][256] f16 (Wq rows scaled), ms4[4][b][n] f32.
// K0 wprep: W->f16 (+log2e on Wq rows).
// K1 qkv: MFMA GEMM, x staged once per (b,n-tile), all 320 rows per block.
// K2 mpass: partial col-max of S' (log2 domain).
// K3 attn: block 64j x 128c; per 64-i tile: wave (jh,ih) does S quarter ->
//   exp2 -> in-register D->B transform (shfl_xor 32) -> PV with v as A-op
//   (D col = j -> coalesced stores). v via swizzled global_load_lds dbuf.
//   ONE barrier per tile. Cross-ih acc reduce via LDS at end.

#define NBATCH 4
#define CDIM   256
#define NSEQ   4096
#define QPDIM  32
#define LOG2E  1.44269504088896340736f

typedef _Float16 half8_t  __attribute__((ext_vector_type(8)));
typedef _Float16 half2_t  __attribute__((ext_vector_type(2)));
typedef float    floatx4  __attribute__((ext_vector_type(4)));
typedef float    floatx16 __attribute__((ext_vector_type(16)));

union H8 { half8_t h8; half2_t h2[4]; int i32[4]; };

__device__ inline half2_t pack_f16(float a, float b) {
    return __builtin_bit_cast(half2_t, __builtin_amdgcn_cvt_pkrtz(a, b));
}

// ---------------------------------------------------------------------------
// K0: W -> f16, Wq rows scaled by log2e. 40 blocks x 256 thr x 8 elems.
// ---------------------------------------------------------------------------
__global__ __launch_bounds__(256) void wprep_kernel(
    const float* __restrict__ Wv, const float* __restrict__ Wq,
    const float* __restrict__ Wk, _Float16* __restrict__ wH)
{
    const int idx = blockIdx.x * 256 + threadIdx.x;
    const int e = idx * 8;
    const int r = e >> 8, c = e & 255;
    const float* src;
    float scale = 1.0f;
    if (r < 256)      src = Wv + (size_t)r * 256 + c;
    else if (r < 288) { src = Wq + (size_t)(r - 256) * 256 + c; scale = LOG2E; }
    else              src = Wk + (size_t)(r - 288) * 256 + c;
    float4 f0 = ((const float4*)src)[0];
    float4 f1 = ((const float4*)src)[1];
    half8_t h;
    h[0] = (_Float16)(f0.x * scale); h[1] = (_Float16)(f0.y * scale);
    h[2] = (_Float16)(f0.z * scale); h[3] = (_Float16)(f0.w * scale);
    h[4] = (_Float16)(f1.x * scale); h[5] = (_Float16)(f1.y * scale);
    h[6] = (_Float16)(f1.z * scale); h[7] = (_Float16)(f1.w * scale);
    *(half8_t*)(wH + (size_t)r * 256 + c) = h;
}

// ---------------------------------------------------------------------------
// K1: qkv GEMM. grid = 4b x 64 nt(64 n) = 256 blocks, 256 thr (4 waves).
// x staged ONCE per block (transposed f16). Wave w: 80 rows (5 m-tiles).
// ---------------------------------------------------------------------------
__global__ __launch_bounds__(256, 2) void qkv_kernel(
    const float* __restrict__ x, const _Float16* __restrict__ wH,
    const float* __restrict__ bq, const float* __restrict__ bk,
    const float* __restrict__ bv,
    _Float16* __restrict__ qH, _Float16* __restrict__ kH,
    _Float16* __restrict__ vHT)
{
    __shared__ _Float16 xT[64][264];   // [n][c]

    const int blk  = blockIdx.x;
    const int slot = blk & 7;
    const int b    = slot >> 1;
    const int n0   = (((blk >> 3) << 1) | (slot & 1)) << 6;  // 64-n tile
    const int t    = threadIdx.x;
    const int w    = t >> 6;
    const int lane = t & 63;
    const int quad = lane >> 4;
    const int col  = lane & 15;

    // ---- stage x[b, :, n0..n0+63] transposed -> f16 ----
    {
        const int crow0 = t >> 4;          // 0..15
        const int npart = t & 15;          // 16 lanes sweep 64 n
        #pragma unroll
        for (int pass = 0; pass < 16; ++pass) {
            const int c = pass * 16 + crow0;
            float4 f = *(const float4*)(
                x + ((size_t)(b * CDIM + c)) * NSEQ + n0 + npart * 4);
            xT[npart * 4 + 0][c] = (_Float16)f.x;
            xT[npart * 4 + 1][c] = (_Float16)f.y;
            xT[npart * 4 + 2][c] = (_Float16)f.z;
            xT[npart * 4 + 3][c] = (_Float16)f.w;
        }
    }
    __syncthreads();

    // ---- GEMM: wave w -> rows w*80 .. +79 (5 m-tiles of 16), 64 n ----
    const int r0 = w * 80;
    floatx4 acc[5][4];
    #pragma unroll
    for (int mt = 0; mt < 5; ++mt)
        #pragma unroll
        for (int nt = 0; nt < 4; ++nt)
            acc[mt][nt] = (floatx4){0.f, 0.f, 0.f, 0.f};

    #pragma unroll
    for (int ks = 0; ks < 8; ++ks) {
        half8_t bf[4];
        #pragma unroll
        for (int nt = 0; nt < 4; ++nt)
            bf[nt] = *(const half8_t*)&xT[nt * 16 + col][ks * 32 + quad * 8];
        #pragma unroll
        for (int mt = 0; mt < 5; ++mt) {
            half8_t a = *(const half8_t*)(
                wH + (size_t)(r0 + mt * 16 + col) * 256 + ks * 32 + quad * 8);
            #pragma unroll
            for (int nt = 0; nt < 4; ++nt)
                acc[mt][nt] = __builtin_amdgcn_mfma_f32_16x16x32_f16(
                    a, bf[nt], acc[mt][nt], 0, 0, 0);
        }
    }

    // ---- epilogue ----
    #pragma unroll
    for (int mt = 0; mt < 5; ++mt) {
        const int gbase = r0 + mt * 16;
        const float* bp; int rl; float bscale = 1.0f;
        if (gbase < 256)      { bp = bv; rl = gbase; }
        else if (gbase < 288) { bp = bq; rl = gbase - 256; bscale = LOG2E; }
        else                  { bp = bk; rl = gbase - 288; }
        #pragma unroll
        for (int reg = 0; reg < 4; ++reg) {
            const int rr = rl + quad * 4 + reg;
            const float bias = bp[rr] * bscale;
            #pragma unroll
            for (int nt = 0; nt < 4; ++nt) {
                const int n = n0 + nt * 16 + col;
                const float val = acc[mt][nt][reg] + bias;
                if (gbase < 256)
                    vHT[((size_t)(b * CDIM + rr)) * NSEQ + n] = (_Float16)val;
                else if (gbase < 288)
                    qH[((size_t)(b * NSEQ + n)) * QPDIM + rr] = (_Float16)val;
                else
                    kH[((size_t)(b * NSEQ + n)) * QPDIM + rr] = (_Float16)val;
            }
        }
    }
}

// ---------------------------------------------------------------------------
// K2: mpass partial col-max (log2 domain). grid = 4iq x 4b x 64 jblk = 1024.
// ---------------------------------------------------------------------------
__global__ __launch_bounds__(256, 4) void mpass_kernel(
    const _Float16* __restrict__ qH, const _Float16* __restrict__ kH,
    float* __restrict__ ms4)
{
    __shared__ float wmax[4][32];

    const int blk  = blockIdx.x;
    const int slot = blk & 7;
    const int b    = slot >> 1;
    const int idx  = ((blk >> 3) << 1) | (slot & 1);
    const int jblk = idx & 63;
    const int iq   = idx >> 6;
    const int t    = threadIdx.x;
    const int w    = t >> 6;
    const int lane = t & 63;
    const int l5   = lane >> 5;
    const int lj   = lane & 31;
    const int jt   = w & 1, ih = w >> 1;

    const _Float16* qg = qH + (size_t)b * NSEQ * QPDIM;
    const int j = jblk * 64 + jt * 32 + lj;
    const half8_t kb0 = *(const half8_t*)(
        kH + ((size_t)(b * NSEQ + j)) * QPDIM + l5 * 8);
    const half8_t kb1 = *(const half8_t*)(
        kH + ((size_t)(b * NSEQ + j)) * QPDIM + 16 + l5 * 8);

    float mx = -1e30f;
    const int ibase = iq * 1024 + ih * 512;
    for (int cc = 0; cc < 16; ++cc) {
        const _Float16* qp = qg + (size_t)(ibase + cc * 32 + lj) * QPDIM + l5 * 8;
        half8_t qa0 = *(const half8_t*)qp;
        half8_t qa1 = *(const half8_t*)(qp + 16);
        floatx16 S = __builtin_amdgcn_mfma_f32_32x32x16_f16(
            qa0, kb0, (floatx16){0.f}, 0, 0, 0);
        S = __builtin_amdgcn_mfma_f32_32x32x16_f16(qa1, kb1, S, 0, 0, 0);
        #pragma unroll
        for (int r = 0; r < 16; ++r) mx = fmaxf(mx, S[r]);
    }
    mx = fmaxf(mx, __shfl_xor(mx, 32));
    if (lane < 32) wmax[w][lane] = mx;
    __syncthreads();
    if (t < 64) {
        const int jt3 = t >> 5, c = t & 31;
        ms4[(size_t)iq * (NBATCH * NSEQ) + (size_t)b * NSEQ
            + jblk * 64 + jt3 * 32 + c] = fmaxf(wmax[jt3][c], wmax[jt3 + 2][c]);
    }
}

// ---------------------------------------------------------------------------
// K3: attn. grid = 512 (4b x 64 jblk(64j) x 2 cb(128c)), 256 thr.
// Wave (jh=w&1, ih=w>>1): S quarter (32j x 32i of the 64-i tile) -> exp2 ->
// in-register transform -> PV: acc[ct](c=ct*32+..) += v(A) x P(B).
// ---------------------------------------------------------------------------
__global__ __launch_bounds__(256, 2) void attn_kernel(
    const _Float16* __restrict__ qH, const _Float16* __restrict__ kH,
    const _Float16* __restrict__ vHT, const float* __restrict__ ms4,
    const float* __restrict__ x, const float* __restrict__ gamma,
    float* __restrict__ out)
{
    __shared__ _Float16 vbuf[2][8192];   // [buf][1024 units of 16B] (32 KB)
    __shared__ float lred2[2][2][32];    // [jh][ih][j]

    const int blk  = blockIdx.x;
    const int slot = blk & 7;
    const int b    = slot >> 1;
    const int idx  = ((blk >> 3) << 1) | (slot & 1);  // 0..127
    const int cb   = idx >> 6;                        // 0..1
    const int jblk = idx & 63;                        // 0..63
    const int j0   = jblk << 6;
    const int c0   = cb << 7;
    const int t    = threadIdx.x;
    const int w    = t >> 6;
    const int lane = t & 63;
    const int l5   = lane >> 5;
    const int lj   = lane & 31;
    const int jh   = w & 1;
    const int ih   = w >> 1;

    const _Float16* qg = qH + (size_t)b * NSEQ * QPDIM;
    const _Float16* vg = vHT + (size_t)b * CDIM * NSEQ;

    // persistent S B-frags (k of this wave's 32-j tile)
    const int jme = j0 + jh * 32 + lj;
    const half8_t kb0 = *(const half8_t*)(
        kH + ((size_t)(b * NSEQ + jme)) * QPDIM + l5 * 8);
    const half8_t kb1 = *(const half8_t*)(
        kH + ((size_t)(b * NSEQ + jme)) * QPDIM + 16 + l5 * 8);
    const float* msb = ms4 + (size_t)b * NSEQ + jme;
    const float mfix = fmaxf(
        fmaxf(msb[0], msb[NBATCH * NSEQ]),
        fmaxf(msb[2 * NBATCH * NSEQ], msb[3 * NBATCH * NSEQ]));

    floatx16 acc[4];
    #pragma unroll
    for (int ct = 0; ct < 4; ++ct) acc[ct] = (floatx16){0.f};
    float lp = 0.0f;

    // v DMA: wave w covers units [w*256, +256) = c_local [w*32, +32)
    #define DMA_V(i0_, buf_)                                                   \
        {                                                                      \
            _Pragma("unroll")                                                  \
            for (int g = 0; g < 4; ++g) {                                      \
                const int uu = w * 256 + g * 64 + lane;                        \
                const int cl = uu >> 3;                                        \
                const int ck = (uu & 7) ^ (cl & 7);                            \
                const _Float16* src =                                          \
                    vg + (size_t)(c0 + cl) * NSEQ + (i0_) + ck * 8;            \
                __builtin_amdgcn_global_load_lds(                              \
                    (const __attribute__((address_space(1))) void*)src,        \
                    (__attribute__((address_space(3))) void*)                  \
                        (&vbuf[buf_][(w * 256 + g * 64) * 8]),                 \
                    16, 0, 0);                                                 \
            }                                                                  \
        }

    DMA_V(0, 0);
    const _Float16* qb = qg + (size_t)(ih * 32 + lj) * QPDIM + l5 * 8;
    half8_t qa0 = *(const half8_t*)(qb);
    half8_t qa1 = *(const half8_t*)(qb + 16);

    int cur = 0;
    for (int i0 = 0; i0 < NSEQ; i0 += 64) {
        __syncthreads();   // vbuf[cur] DMA'd; prev reads of vbuf[cur^1] done
        if (i0 + 64 < NSEQ) DMA_V(i0 + 64, cur ^ 1);

        // ---- S quarter: D[m=i][n=j], lane j = lj, regs = i ----
        floatx16 S = __builtin_amdgcn_mfma_f32_32x32x16_f16(
            qa0, kb0, (floatx16){0.f}, 0, 0, 0);
        S = __builtin_amdgcn_mfma_f32_32x32x16_f16(qa1, kb1, S, 0, 0, 0);

        // exp2 + pack (log2 domain: single v_exp per element)
        H8 lo, hi;
        float ls = 0.0f;
        #pragma unroll
        for (int p = 0; p < 4; ++p) {
            float pa = __builtin_amdgcn_exp2f(S[2 * p]     - mfix);
            float pb = __builtin_amdgcn_exp2f(S[2 * p + 1] - mfix);
            ls += pa + pb;
            lo.h2[p] = pack_f16(pa, pb);
        }
        #pragma unroll
        for (int p = 0; p < 4; ++p) {
            float pa = __builtin_amdgcn_exp2f(S[8 + 2 * p]     - mfix);
            float pb = __builtin_amdgcn_exp2f(S[8 + 2 * p + 1] - mfix);
            ls += pa + pb;
            hi.h2[p] = pack_f16(pa, pb);
        }
        lp += ls;

        // D -> operand transform (verified R4): shfl_xor 32 + select
        H8 shl, shh;
        #pragma unroll
        for (int r = 0; r < 4; ++r) {
            shl.i32[r] = __shfl_xor(lo.i32[r], 32);
            shh.i32[r] = __shfl_xor(hi.i32[r], 32);
        }
        const bool high = (l5 != 0);
        H8 P0, P1;   // B-operand frags: k = i 0..15 / 16..31 of wave's chunk
        P0.i32[0] = high ? shl.i32[2] : lo.i32[0];
        P0.i32[1] = high ? shl.i32[3] : lo.i32[1];
        P0.i32[2] = high ? lo.i32[2]  : shl.i32[0];
        P0.i32[3] = high ? lo.i32[3]  : shl.i32[1];
        P1.i32[0] = high ? shh.i32[2] : hi.i32[0];
        P1.i32[1] = high ? shh.i32[3] : hi.i32[1];
        P1.i32[2] = high ? hi.i32[2]  : shh.i32[0];
        P1.i32[3] = high ? hi.i32[3]  : shh.i32[1];

        // ---- PV: acc[ct] (D[m=c][n=j]) += v(A) . P(B) ----
        #pragma unroll
        for (int ct = 0; ct < 4; ++ct) {
            const int cl = ct * 32 + lj;
            const int ic0 = (ih * 4 + 0 + l5) ^ (cl & 7);   // ks=0 chunk
            const int ic1 = (ih * 4 + 2 + l5) ^ (cl & 7);   // ks=1 chunk
            half8_t va0 = *(const half8_t*)&vbuf[cur][(cl * 8 + ic0) * 8];
            half8_t va1 = *(const half8_t*)&vbuf[cur][(cl * 8 + ic1) * 8];
            acc[ct] = __builtin_amdgcn_mfma_f32_32x32x16_f16(
                va0, P0.h8, acc[ct], 0, 0, 0);
            acc[ct] = __builtin_amdgcn_mfma_f32_32x32x16_f16(
                va1, P1.h8, acc[ct], 0, 0, 0);
        }

        // prefetch next q frags (drained by next barrier)
        if (i0 + 64 < NSEQ) {
            qa0 = *(const half8_t*)(qb + (size_t)(i0 + 64) * QPDIM);
            qa1 = *(const half8_t*)(qb + (size_t)(i0 + 64) * QPDIM + 16);
        }
        cur ^= 1;
    }

    // ---- reductions: l across (l5, ih); acc across ih via LDS ----
    lp += __shfl_xor(lp, 32);
    if (lane < 32) lred2[jh][ih][lane] = lp;

    float* fred = (float*)vbuf;   // 8192 floats = 32 KB, reuse vbuf
    if (ih == 1) {
        #pragma unroll
        for (int ct = 0; ct < 4; ++ct)
            #pragma unroll
            for (int reg = 0; reg < 16; ++reg) {
                const int crow = (reg & 3) + 8 * (reg >> 2) + 4 * l5;
                fred[(ct * 32 + crow) * 64 + jh * 32 + lj] = acc[ct][reg];
            }
    }
    __syncthreads();

    if (ih == 0) {
        const float rv = gamma[0] / (lred2[jh][0][lj] + lred2[jh][1][lj]);
        #pragma unroll
        for (int ct = 0; ct < 4; ++ct) {
            #pragma unroll
            for (int reg = 0; reg < 16; ++reg) {
                const int crow = (reg & 3) + 8 * (reg >> 2) + 4 * l5;
                const int c_ = c0 + ct * 32 + crow;
                const size_t off = ((size_t)(b * CDIM + c_)) * NSEQ + jme;
                const float sum =
                    acc[ct][reg] + fred[(ct * 32 + crow) * 64 + jh * 32 + lj];
                out[off] = sum * rv + x[off];
            }
        }
    }
}

extern "C" void kernel_launch(void* const* d_in, const int* in_sizes, int n_in,
                              void* d_out, int out_size, void* d_ws, size_t ws_size,
                              hipStream_t stream) {
    const float* x     = (const float*)d_in[0];
    const float* Wq    = (const float*)d_in[1];
    const float* bq    = (const float*)d_in[2];
    const float* Wk    = (const float*)d_in[3];
    const float* bk    = (const float*)d_in[4];
    const float* Wv    = (const float*)d_in[5];
    const float* bv    = (const float*)d_in[6];
    const float* gamma = (const float*)d_in[7];
    float* out = (float*)d_out;

    _Float16* w16 = (_Float16*)d_ws;
    _Float16* qH  = w16;                                        // 1 MB
    _Float16* kH  = qH + (size_t)NBATCH * NSEQ * QPDIM;         // 1 MB
    _Float16* vHT = kH + (size_t)NBATCH * NSEQ * QPDIM;         // 8 MB
    _Float16* wH  = vHT + (size_t)NBATCH * CDIM * NSEQ;         // 160 KB
    float*    ms4 = (float*)(wH + (size_t)320 * 256);           // 256 KB

    wprep_kernel<<<40, 256, 0, stream>>>(Wv, Wq, Wk, wH);
    qkv_kernel<<<256, 256, 0, stream>>>(x, wH, bq, bk, bv, qH, kH, vHT);
    mpass_kernel<<<1024, 256, 0, stream>>>(qH, kH, ms4);
    attn_kernel<<<512, 256, 0, stream>>>(qH, kH, vHT, ms4, x, gamma, out);
}